// Round 1
// baseline (1981.046 us; speedup 1.0000x reference)
//
#include <hip/hip_runtime.h>
#include <hip/hip_bf16.h>
#include <math.h>

// Problem constants: B=1, N=512, FN=8, FE=1, E=32, D0=14, 8 frames.
#define NN 512
#define EE 32

// ---------------------------------------------------------------------------
// K1: center + covariance + 3x3 Jacobi eigh (double), writes center[3], V[9]
// ws layout written: ws[0..2]=center, ws[3+r*3+c]=V[r][c] (cols ascending eig)
// ---------------------------------------------------------------------------
__global__ void __launch_bounds__(256) frame_kernel(const float* __restrict__ x,
                                                    float* __restrict__ ws) {
    __shared__ double red[4][9];
    int t = threadIdx.x;
    double s[9] = {0,0,0,0,0,0,0,0,0};
    for (int n = t; n < NN; n += 256) {
        double X = x[n*3+0], Y = x[n*3+1], Z = x[n*3+2];
        s[0]+=X; s[1]+=Y; s[2]+=Z;
        s[3]+=X*X; s[4]+=X*Y; s[5]+=X*Z; s[6]+=Y*Y; s[7]+=Y*Z; s[8]+=Z*Z;
    }
    #pragma unroll
    for (int m = 1; m < 64; m <<= 1) {
        #pragma unroll
        for (int q = 0; q < 9; ++q) s[q] += __shfl_xor(s[q], m);
    }
    int wave = t >> 6, lane = t & 63;
    if (lane == 0) {
        #pragma unroll
        for (int q = 0; q < 9; ++q) red[wave][q] = s[q];
    }
    __syncthreads();
    if (t == 0) {
        double S[9];
        #pragma unroll
        for (int q = 0; q < 9; ++q) S[q] = red[0][q]+red[1][q]+red[2][q]+red[3][q];
        double cx = S[0]/512.0, cy = S[1]/512.0, cz = S[2]/512.0;
        double A[3][3];
        A[0][0]=S[3]-512.0*cx*cx; A[0][1]=S[4]-512.0*cx*cy; A[0][2]=S[5]-512.0*cx*cz;
        A[1][1]=S[6]-512.0*cy*cy; A[1][2]=S[7]-512.0*cy*cz; A[2][2]=S[8]-512.0*cz*cz;
        A[1][0]=A[0][1]; A[2][0]=A[0][2]; A[2][1]=A[1][2];
        double V[3][3] = {{1,0,0},{0,1,0},{0,0,1}};
        for (int sweep = 0; sweep < 8; ++sweep) {
            double off = fabs(A[0][1]) + fabs(A[0][2]) + fabs(A[1][2]);
            double dia = fabs(A[0][0]) + fabs(A[1][1]) + fabs(A[2][2]);
            if (off < 1e-14 * (dia + 1e-300)) break;
            for (int p = 0; p < 3; ++p) for (int q = p+1; q < 3; ++q) {
                double apq = A[p][q];
                if (fabs(apq) < 1e-300) continue;
                double tau = (A[q][q] - A[p][p]) / (2.0 * apq);
                double tt = (tau >= 0 ? 1.0 : -1.0) / (fabs(tau) + sqrt(1.0 + tau*tau));
                double cc = 1.0 / sqrt(1.0 + tt*tt), ss = tt * cc;
                double app = A[p][p], aqq = A[q][q];
                A[p][p] = app - tt * apq;
                A[q][q] = aqq + tt * apq;
                A[p][q] = 0.0; A[q][p] = 0.0;
                for (int k = 0; k < 3; ++k) if (k != p && k != q) {
                    double akp = A[k][p], akq = A[k][q];
                    A[k][p] = cc*akp - ss*akq; A[p][k] = A[k][p];
                    A[k][q] = ss*akp + cc*akq; A[q][k] = A[k][q];
                }
                for (int k = 0; k < 3; ++k) {
                    double vkp = V[k][p], vkq = V[k][q];
                    V[k][p] = cc*vkp - ss*vkq;
                    V[k][q] = ss*vkp + cc*vkq;
                }
            }
        }
        double ev[3] = {A[0][0], A[1][1], A[2][2]};
        int idx[3] = {0,1,2};
        for (int a = 0; a < 2; ++a) for (int b = a+1; b < 3; ++b)
            if (ev[idx[b]] < ev[idx[a]]) { int tmp = idx[a]; idx[a] = idx[b]; idx[b] = tmp; }
        ws[0] = (float)cx; ws[1] = (float)cy; ws[2] = (float)cz;
        for (int r = 0; r < 3; ++r)
            for (int c = 0; c < 3; ++c)
                ws[3 + r*3 + c] = (float)V[r][idx[c]];
    }
}

// ---------------------------------------------------------------------------
// K2: build h0[8][512][14] = concat(fx, fv, node_feat); fx = sign .* (V^T xc)
// ---------------------------------------------------------------------------
__global__ void __launch_bounds__(256) h0_kernel(const float* __restrict__ x,
                                                 const float* __restrict__ v,
                                                 const float* __restrict__ nf,
                                                 const float* __restrict__ ws,
                                                 float* __restrict__ h0) {
    int t = blockIdx.x * 256 + threadIdx.x;     // 0..4095
    int o = t >> 9, n = t & 511;
    float xc0 = x[n*3+0] - ws[0], xc1 = x[n*3+1] - ws[1], xc2 = x[n*3+2] - ws[2];
    float v0 = v[n*3+0], v1 = v[n*3+1], v2 = v[n*3+2];
    float* outp = h0 + t * 14;
    #pragma unroll
    for (int i = 0; i < 3; ++i) {
        float sgn = ((o >> (2 - i)) & 1) ? -1.f : 1.f;
        float px = ws[3 + 0*3 + i]*xc0 + ws[3 + 1*3 + i]*xc1 + ws[3 + 2*3 + i]*xc2;
        float pv = ws[3 + 0*3 + i]*v0  + ws[3 + 1*3 + i]*v1  + ws[3 + 2*3 + i]*v2;
        outp[i]     = sgn * px;
        outp[3 + i] = sgn * pv;
    }
    #pragma unroll
    for (int k = 0; k < 8; ++k) outp[6 + k] = nf[n*8 + k];
}

// ---------------------------------------------------------------------------
// K3a: pre-projections. prejT[k][o][j] = (h @ ew1[1:1+D])[o,j,k]
//      preib[o*512+j][c] = (h @ ew1[1+D:1+2D])[o,j,c] + eb1[c]
// ---------------------------------------------------------------------------
template<int D>
__global__ void __launch_bounds__(256) pre_kernel(const float* __restrict__ h,
                                                  const float* __restrict__ ew1,
                                                  const float* __restrict__ eb1,
                                                  float* __restrict__ prejT,
                                                  float* __restrict__ preib) {
    int t = blockIdx.x * 256 + threadIdx.x;   // 0..131071
    int c = t & 31, row = t >> 5;             // row = o*512+j
    int o = row >> 9, j = row & 511;
    const float* hr = h + row * D;
    float pj = 0.f, pi = eb1[c];
    #pragma unroll
    for (int k = 0; k < D; ++k) {
        float hv = hr[k];
        pj = fmaf(hv, ew1[(1 + k) * 32 + c], pj);
        pi = fmaf(hv, ew1[(1 + D + k) * 32 + c], pi);
    }
    prejT[c * 4096 + o * 512 + j] = pj;
    preib[row * 32 + c] = pi;
}

// ---------------------------------------------------------------------------
// K3b: edge MLP + aggregation + node MLP. One wave per (o,i); lane owns j's.
// W2/we/eb2 accessed at wave-uniform addresses -> scalar loads (SGPR operands).
// ---------------------------------------------------------------------------
template<int D>
__global__ void __launch_bounds__(256) edge_kernel(
    const float* __restrict__ prejT,   // [32][8][512]
    const float* __restrict__ preib,   // [8*512][32] (includes +eb1)
    const float* __restrict__ edge,    // [512][512]
    const float* __restrict__ h,       // [8*512][D]
    const float* __restrict__ ew1,     // row 0 = we[32]
    const float* __restrict__ ew2,     // [32][32]
    const float* __restrict__ eb2,
    const float* __restrict__ nw1,     // [D+32][32]
    const float* __restrict__ nb1,
    const float* __restrict__ nw2,     // [32][32]
    const float* __restrict__ nb2,
    float* __restrict__ hout)          // [8*512][32]
{
    const int t = threadIdx.x;
    const int wv = t >> 6, lane = t & 63;
    const int gw = blockIdx.x * 4 + wv;       // 0..4095
    const int o = gw >> 9, i = gw & 511;
    const int row = (o << 9) | i;
    const float* pib = preib + row * 32;      // wave-uniform base
    const float* pjT = prejT + (o << 9);
    float agg[32];
    #pragma unroll
    for (int c = 0; c < 32; ++c) agg[c] = 0.f;

    #pragma unroll 1
    for (int jj = 0; jj < 8; ++jj) {
        const int j = (jj << 6) | lane;
        const float e = edge[(i << 9) | j];
        float m1[32];
        #pragma unroll
        for (int k = 0; k < 32; ++k) {
            float a = fmaf(e, ew1[k], pib[k] + pjT[k * 4096 + j]);
            m1[k] = fmaxf(a, 0.f);
        }
        #pragma unroll
        for (int c = 0; c < 32; ++c) {
            float acc = eb2[c];
            #pragma unroll
            for (int k = 0; k < 32; ++k)
                acc = fmaf(m1[k], ew2[k * 32 + c], acc);
            agg[c] += fmaxf(acc, 0.f);
        }
    }
    // all-lane reduction: every lane ends with the full sum for every c
    #pragma unroll
    for (int c = 0; c < 32; ++c) {
        float vs = agg[c];
        vs += __shfl_xor(vs, 1);
        vs += __shfl_xor(vs, 2);
        vs += __shfl_xor(vs, 4);
        vs += __shfl_xor(vs, 8);
        vs += __shfl_xor(vs, 16);
        vs += __shfl_xor(vs, 32);
        agg[c] = vs;
    }
    // node MLP tail (both wave halves duplicate; lanes<32 store)
    const int c = lane & 31;
    const float* hr = h + row * D;
    float acc = nb1[c];
    #pragma unroll
    for (int k = 0; k < D; ++k) acc = fmaf(hr[k], nw1[k * 32 + c], acc);
    #pragma unroll
    for (int k = 0; k < 32; ++k) acc = fmaf(agg[k], nw1[(D + k) * 32 + c], acc);
    const float dn = fmaxf(acc, 0.f);
    float outv = nb2[c];
    #pragma unroll
    for (int k = 0; k < 32; ++k)
        outv = fmaf(__shfl(dn, k, 32), nw2[k * 32 + c], outv);
    if (lane < 32) hout[row * 32 + c] = outv;
}

// ---------------------------------------------------------------------------
// K4a: decoder -> so6[8*512][6]. One wave per (o,n) row.
// ---------------------------------------------------------------------------
__global__ void __launch_bounds__(256) dec_kernel(const float* __restrict__ h2,
                                                  const float* __restrict__ w1,
                                                  const float* __restrict__ b1,
                                                  const float* __restrict__ w2,   // [32][6]
                                                  const float* __restrict__ b2,
                                                  float* __restrict__ so6) {
    int t = threadIdx.x;
    int wave = t >> 6, lane = t & 63;
    int row = blockIdx.x * 4 + wave;   // 0..4095
    int c = lane & 31;
    float hv = h2[row * 32 + c];
    float rh = fmaxf(hv, 0.f);
    float acc = b1[c];
    #pragma unroll
    for (int k = 0; k < 32; ++k)
        acc = fmaf(__shfl(rh, k, 32), w1[k * 32 + c], acc);
    float s = fmaxf(acc, 0.f);
    #pragma unroll
    for (int m = 0; m < 6; ++m) {
        float p = s * w2[c * 6 + m];
        p += __shfl_xor(p, 1); p += __shfl_xor(p, 2); p += __shfl_xor(p, 4);
        p += __shfl_xor(p, 8); p += __shfl_xor(p, 16);
        if (lane == 0) so6[row * 6 + m] = p + b2[m];
    }
}

// ---------------------------------------------------------------------------
// K4b: h_mean + coef MLP + invert_frame + x_out/v_out. One wave per node.
// ---------------------------------------------------------------------------
__global__ void __launch_bounds__(256) final_kernel(const float* __restrict__ h2,
                                                    const float* __restrict__ so6,
                                                    const float* __restrict__ x,
                                                    const float* __restrict__ v,
                                                    const float* __restrict__ ws,
                                                    const float* __restrict__ vw1,
                                                    const float* __restrict__ vb1,
                                                    const float* __restrict__ vw2,
                                                    const float* __restrict__ vb2,
                                                    float* __restrict__ out_hmean,
                                                    float* __restrict__ out_x,
                                                    float* __restrict__ out_v) {
    int t = threadIdx.x;
    int wave = t >> 6, lane = t & 63;
    int n = blockIdx.x * 4 + wave;   // 0..511
    int c = lane & 31;
    float hm = 0.f;
    #pragma unroll
    for (int o = 0; o < 8; ++o) hm += h2[(o * 512 + n) * 32 + c];
    hm *= 0.125f;
    if (lane < 32) out_hmean[n * 32 + c] = hm;
    float rh = fmaxf(hm, 0.f);
    float acc = vb1[c];
    #pragma unroll
    for (int k = 0; k < 32; ++k)
        acc = fmaf(__shfl(rh, k, 32), vw1[k * 32 + c], acc);
    float t1 = fmaxf(acc, 0.f);
    float p = t1 * vw2[c];
    p += __shfl_xor(p, 1); p += __shfl_xor(p, 2); p += __shfl_xor(p, 4);
    p += __shfl_xor(p, 8); p += __shfl_xor(p, 16);
    float coef = p + vb2[0];
    if (lane < 3) {
        int i = lane;
        float dx = 0.f, dv = 0.f;
        #pragma unroll
        for (int o = 0; o < 8; ++o) {
            #pragma unroll
            for (int j = 0; j < 3; ++j) {
                float sgn = ((o >> (2 - j)) & 1) ? -1.f : 1.f;
                float f = sgn * ws[3 + i * 3 + j];
                dx = fmaf(f, so6[(o * 512 + n) * 6 + j], dx);
                dv = fmaf(f, so6[(o * 512 + n) * 6 + 3 + j], dv);
            }
        }
        dx *= 0.125f; dv *= 0.125f;
        float vout = v[n * 3 + i] + dv;
        out_v[n * 3 + i] = vout;
        out_x[n * 3 + i] = x[n * 3 + i] + vout * coef + dx;
    }
}

// ---------------------------------------------------------------------------
extern "C" void kernel_launch(void* const* d_in, const int* in_sizes, int n_in,
                              void* d_out, int out_size, void* d_ws, size_t ws_size,
                              hipStream_t stream) {
    const float* node_feat = (const float*)d_in[0];
    const float* edge      = (const float*)d_in[1];
    const float* x         = (const float*)d_in[2];
    const float* v         = (const float*)d_in[3];
    const float* e0_w1 = (const float*)d_in[4];
    const float* e0_b1 = (const float*)d_in[5];
    const float* e0_w2 = (const float*)d_in[6];
    const float* e0_b2 = (const float*)d_in[7];
    const float* n0_w1 = (const float*)d_in[8];
    const float* n0_b1 = (const float*)d_in[9];
    const float* n0_w2 = (const float*)d_in[10];
    const float* n0_b2 = (const float*)d_in[11];
    const float* e1_w1 = (const float*)d_in[12];
    const float* e1_b1 = (const float*)d_in[13];
    const float* e1_w2 = (const float*)d_in[14];
    const float* e1_b2 = (const float*)d_in[15];
    const float* n1_w1 = (const float*)d_in[16];
    const float* n1_b1 = (const float*)d_in[17];
    const float* n1_w2 = (const float*)d_in[18];
    const float* n1_b2 = (const float*)d_in[19];
    const float* dec_w1 = (const float*)d_in[20];
    const float* dec_b1 = (const float*)d_in[21];
    const float* dec_w2 = (const float*)d_in[22];
    const float* dec_b2 = (const float*)d_in[23];
    const float* vc_w1 = (const float*)d_in[24];
    const float* vc_b1 = (const float*)d_in[25];
    const float* vc_w2 = (const float*)d_in[26];
    const float* vc_b2 = (const float*)d_in[27];

    float* ws  = (float*)d_ws;
    float* out = (float*)d_out;

    float* FR  = ws;                 // 16 floats (center + V)
    float* H0  = ws + 16;            // 8*512*14 = 57344
    float* HA  = H0 + 57344;         // 8*512*32 = 131072
    float* HB  = HA + 131072;        // 131072
    float* PJT = HB + 131072;        // 131072
    float* PIB = PJT + 131072;       // 131072
    float* SO6 = PIB + 131072;       // 8*512*6 = 24576

    // Output 1: edge_feat passthrough
    hipMemcpyAsync(out + 16384, edge, (size_t)262144 * sizeof(float),
                   hipMemcpyDeviceToDevice, stream);

    frame_kernel<<<1, 256, 0, stream>>>(x, FR);
    h0_kernel<<<16, 256, 0, stream>>>(x, v, node_feat, FR, H0);

    // Layer 0 (D=14)
    pre_kernel<14><<<512, 256, 0, stream>>>(H0, e0_w1, e0_b1, PJT, PIB);
    edge_kernel<14><<<1024, 256, 0, stream>>>(PJT, PIB, edge, H0, e0_w1, e0_w2,
                                              e0_b2, n0_w1, n0_b1, n0_w2, n0_b2, HA);
    // Layer 1 (D=32)
    pre_kernel<32><<<512, 256, 0, stream>>>(HA, e1_w1, e1_b1, PJT, PIB);
    edge_kernel<32><<<1024, 256, 0, stream>>>(PJT, PIB, edge, HA, e1_w1, e1_w2,
                                              e1_b2, n1_w1, n1_b1, n1_w2, n1_b2, HB);
    // Decoder + outputs
    dec_kernel<<<1024, 256, 0, stream>>>(HB, dec_w1, dec_b1, dec_w2, dec_b2, SO6);
    final_kernel<<<128, 256, 0, stream>>>(HB, SO6, x, v, FR, vc_w1, vc_b1, vc_w2,
                                          vc_b2, out, out + 278528, out + 280064);
}

// Round 2
// 205.545 us; speedup vs baseline: 9.6380x; 9.6380x over previous
//
#include <hip/hip_runtime.h>
#include <hip/hip_bf16.h>
#include <math.h>

// Problem constants: B=1, N=512, FN=8, FE=1, E=32, D0=14, 8 frames.
#define NN 512
#define EE 32

typedef short bf16x8 __attribute__((ext_vector_type(8)));
typedef float f32x4  __attribute__((ext_vector_type(4)));

// RNE float->bf16 (bit pattern in a short)
static __device__ __forceinline__ short f2bf(float f) {
    unsigned u = __builtin_bit_cast(unsigned, f);
    u += 0x7fffu + ((u >> 16) & 1u);
    return (short)(u >> 16);
}

// ---------------------------------------------------------------------------
// K1: center + covariance + 3x3 Jacobi eigh (double), writes center[3], V[9]
// ws layout written: ws[0..2]=center, ws[3+r*3+c]=V[r][c] (cols ascending eig)
// ---------------------------------------------------------------------------
__global__ void __launch_bounds__(256) frame_kernel(const float* __restrict__ x,
                                                    float* __restrict__ ws) {
    __shared__ double red[4][9];
    int t = threadIdx.x;
    double s[9] = {0,0,0,0,0,0,0,0,0};
    for (int n = t; n < NN; n += 256) {
        double X = x[n*3+0], Y = x[n*3+1], Z = x[n*3+2];
        s[0]+=X; s[1]+=Y; s[2]+=Z;
        s[3]+=X*X; s[4]+=X*Y; s[5]+=X*Z; s[6]+=Y*Y; s[7]+=Y*Z; s[8]+=Z*Z;
    }
    #pragma unroll
    for (int m = 1; m < 64; m <<= 1) {
        #pragma unroll
        for (int q = 0; q < 9; ++q) s[q] += __shfl_xor(s[q], m);
    }
    int wave = t >> 6, lane = t & 63;
    if (lane == 0) {
        #pragma unroll
        for (int q = 0; q < 9; ++q) red[wave][q] = s[q];
    }
    __syncthreads();
    if (t == 0) {
        double S[9];
        #pragma unroll
        for (int q = 0; q < 9; ++q) S[q] = red[0][q]+red[1][q]+red[2][q]+red[3][q];
        double cx = S[0]/512.0, cy = S[1]/512.0, cz = S[2]/512.0;
        double A[3][3];
        A[0][0]=S[3]-512.0*cx*cx; A[0][1]=S[4]-512.0*cx*cy; A[0][2]=S[5]-512.0*cx*cz;
        A[1][1]=S[6]-512.0*cy*cy; A[1][2]=S[7]-512.0*cy*cz; A[2][2]=S[8]-512.0*cz*cz;
        A[1][0]=A[0][1]; A[2][0]=A[0][2]; A[2][1]=A[1][2];
        double V[3][3] = {{1,0,0},{0,1,0},{0,0,1}};
        for (int sweep = 0; sweep < 8; ++sweep) {
            double off = fabs(A[0][1]) + fabs(A[0][2]) + fabs(A[1][2]);
            double dia = fabs(A[0][0]) + fabs(A[1][1]) + fabs(A[2][2]);
            if (off < 1e-14 * (dia + 1e-300)) break;
            for (int p = 0; p < 3; ++p) for (int q = p+1; q < 3; ++q) {
                double apq = A[p][q];
                if (fabs(apq) < 1e-300) continue;
                double tau = (A[q][q] - A[p][p]) / (2.0 * apq);
                double tt = (tau >= 0 ? 1.0 : -1.0) / (fabs(tau) + sqrt(1.0 + tau*tau));
                double cc = 1.0 / sqrt(1.0 + tt*tt), ss = tt * cc;
                double app = A[p][p], aqq = A[q][q];
                A[p][p] = app - tt * apq;
                A[q][q] = aqq + tt * apq;
                A[p][q] = 0.0; A[q][p] = 0.0;
                for (int k = 0; k < 3; ++k) if (k != p && k != q) {
                    double akp = A[k][p], akq = A[k][q];
                    A[k][p] = cc*akp - ss*akq; A[p][k] = A[k][p];
                    A[k][q] = ss*akp + cc*akq; A[q][k] = A[k][q];
                }
                for (int k = 0; k < 3; ++k) {
                    double vkp = V[k][p], vkq = V[k][q];
                    V[k][p] = cc*vkp - ss*vkq;
                    V[k][q] = ss*vkp + cc*vkq;
                }
            }
        }
        double ev[3] = {A[0][0], A[1][1], A[2][2]};
        int idx[3] = {0,1,2};
        for (int a = 0; a < 2; ++a) for (int b = a+1; b < 3; ++b)
            if (ev[idx[b]] < ev[idx[a]]) { int tmp = idx[a]; idx[a] = idx[b]; idx[b] = tmp; }
        ws[0] = (float)cx; ws[1] = (float)cy; ws[2] = (float)cz;
        for (int r = 0; r < 3; ++r)
            for (int c = 0; c < 3; ++c)
                ws[3 + r*3 + c] = (float)V[r][idx[c]];
    }
}

// ---------------------------------------------------------------------------
// K2: build h0[8][512][14] = concat(fx, fv, node_feat); fx = sign .* (V^T xc)
// ---------------------------------------------------------------------------
__global__ void __launch_bounds__(256) h0_kernel(const float* __restrict__ x,
                                                 const float* __restrict__ v,
                                                 const float* __restrict__ nf,
                                                 const float* __restrict__ ws,
                                                 float* __restrict__ h0) {
    int t = blockIdx.x * 256 + threadIdx.x;     // 0..4095
    int o = t >> 9, n = t & 511;
    float xc0 = x[n*3+0] - ws[0], xc1 = x[n*3+1] - ws[1], xc2 = x[n*3+2] - ws[2];
    float v0 = v[n*3+0], v1 = v[n*3+1], v2 = v[n*3+2];
    float* outp = h0 + t * 14;
    #pragma unroll
    for (int i = 0; i < 3; ++i) {
        float sgn = ((o >> (2 - i)) & 1) ? -1.f : 1.f;
        float px = ws[3 + 0*3 + i]*xc0 + ws[3 + 1*3 + i]*xc1 + ws[3 + 2*3 + i]*xc2;
        float pv = ws[3 + 0*3 + i]*v0  + ws[3 + 1*3 + i]*v1  + ws[3 + 2*3 + i]*v2;
        outp[i]     = sgn * px;
        outp[3 + i] = sgn * pv;
    }
    #pragma unroll
    for (int k = 0; k < 8; ++k) outp[6 + k] = nf[n*8 + k];
}

// ---------------------------------------------------------------------------
// K3a: pre-projections, row-major.
//   PJ [o*512+j][k]  = (h @ ew1[1:1+D])[o,j,k]
//   PIB[o*512+j][k]  = (h @ ew1[1+D:1+2D])[o,j,k] + eb1[k]
// ---------------------------------------------------------------------------
template<int D>
__global__ void __launch_bounds__(256) pre_kernel(const float* __restrict__ h,
                                                  const float* __restrict__ ew1,
                                                  const float* __restrict__ eb1,
                                                  float* __restrict__ PJ,
                                                  float* __restrict__ PIB) {
    int t = blockIdx.x * 256 + threadIdx.x;   // 0..131071
    int c = t & 31, row = t >> 5;             // row = o*512+j
    const float* hr = h + row * D;
    float pj = 0.f, pi = eb1[c];
    #pragma unroll
    for (int k = 0; k < D; ++k) {
        float hv = hr[k];
        pj = fmaf(hv, ew1[(1 + k) * 32 + c], pj);
        pi = fmaf(hv, ew1[(1 + D + k) * 32 + c], pi);
    }
    PJ[row * 32 + c] = pj;
    PIB[row * 32 + c] = pi;
}

// ---------------------------------------------------------------------------
// K3b: edge MLP (MFMA) + aggregation + node MLP. One wave per (o,i).
//  m1 computed per-lane directly in MFMA A-fragment layout:
//    A[m = lane&15][k = (lane>>4)*8 + e]  (m indexes j within 16-row tile)
//  B fragment: W2[k = (lane>>4)*8 + e][n = lane&15 (+16 for upper half)]
//  C/D: col = lane&15 (c), row = (lane>>4)*4 + reg (j within tile)
// ---------------------------------------------------------------------------
template<int D>
__global__ void __launch_bounds__(256) edge_kernel(
    const float* __restrict__ PJ,      // [8*512][32]
    const float* __restrict__ PIB,     // [8*512][32] (includes +eb1)
    const float* __restrict__ edge,    // [512][512]
    const float* __restrict__ h,       // [8*512][D]
    const float* __restrict__ ew1,     // row 0 = we[32]
    const float* __restrict__ ew2,     // [32][32]
    const float* __restrict__ eb2,
    const float* __restrict__ nw1,     // [D+32][32]
    const float* __restrict__ nb1,
    const float* __restrict__ nw2,     // [32][32]
    const float* __restrict__ nb2,
    float* __restrict__ hout)          // [8*512][32]
{
    const int t = threadIdx.x;
    const int wv = t >> 6, lane = t & 63;
    const int gw = blockIdx.x * 4 + wv;       // 0..4095
    const int o = gw >> 9, i = gw & 511;
    const int row = (o << 9) | i;
    const int l15 = lane & 15;
    const int kbase = (lane >> 4) * 8;        // quad*8

    // Hoisted per-lane constants (fp32): pre_i (+eb1) and we for this lane's 8 k's
    float pi_f[8], we_f[8];
    #pragma unroll
    for (int e = 0; e < 8; ++e) {
        pi_f[e] = PIB[row * 32 + kbase + e];
        we_f[e] = ew1[kbase + e];             // ew1 row 0
    }
    // B fragments (W2), loaded once per wave
    bf16x8 bfrag0, bfrag1;
    #pragma unroll
    for (int e = 0; e < 8; ++e) {
        bfrag0[e] = f2bf(ew2[(kbase + e) * 32 + l15]);
        bfrag1[e] = f2bf(ew2[(kbase + e) * 32 + l15 + 16]);
    }
    const float b2v0 = eb2[l15], b2v1 = eb2[l15 + 16];
    float agg0 = 0.f, agg1 = 0.f;

    const float* edge_i = edge + (i << 9);
    const float* pj_o   = PJ + ((size_t)(o << 9)) * 32;

    for (int jj = 0; jj < 8; ++jj) {
        // Build 4 A-fragments (M-tiles of 16 j's each)
        bf16x8 afrag[4];
        #pragma unroll
        for (int jm = 0; jm < 4; ++jm) {
            const int j = (jj << 6) + (jm << 4) + l15;
            const float e_ij = edge_i[j];
            const float* pjr = pj_o + j * 32 + kbase;
            #pragma unroll
            for (int e = 0; e < 8; ++e) {
                float m1 = fmaf(e_ij, we_f[e], pjr[e] + pi_f[e]);
                afrag[jm][e] = f2bf(fmaxf(m1, 0.f));
            }
        }
        // 8 MFMAs: 4 M-tiles x 2 N-halves; relu + accumulate sum over j
        #pragma unroll
        for (int jm = 0; jm < 4; ++jm) {
            f32x4 c0 = {0.f, 0.f, 0.f, 0.f};
            c0 = __builtin_amdgcn_mfma_f32_16x16x32_bf16(afrag[jm], bfrag0, c0, 0, 0, 0);
            #pragma unroll
            for (int r = 0; r < 4; ++r) agg0 += fmaxf(c0[r] + b2v0, 0.f);
            f32x4 c1 = {0.f, 0.f, 0.f, 0.f};
            c1 = __builtin_amdgcn_mfma_f32_16x16x32_bf16(afrag[jm], bfrag1, c1, 0, 0, 0);
            #pragma unroll
            for (int r = 0; r < 4; ++r) agg1 += fmaxf(c1[r] + b2v1, 0.f);
        }
    }
    // Sum the quad-partials (rows): lanes l, l^16, l^32, l^48 share column l15
    agg0 += __shfl_xor(agg0, 16); agg0 += __shfl_xor(agg0, 32);
    agg1 += __shfl_xor(agg1, 16); agg1 += __shfl_xor(agg1, 32);
    // Now every lane holds agg[c] for c=l15 (agg0) and c=l15+16 (agg1).

    // Node MLP tail: lane computes output channel c2 = lane&31
    const int c2 = lane & 31;
    const float* hr = h + row * D;
    float acc = nb1[c2];
    #pragma unroll
    for (int k = 0; k < D; ++k) acc = fmaf(hr[k], nw1[k * 32 + c2], acc);
    #pragma unroll
    for (int k = 0; k < 16; ++k)
        acc = fmaf(__shfl(agg0, k, 64), nw1[(D + k) * 32 + c2], acc);
    #pragma unroll
    for (int k = 0; k < 16; ++k)
        acc = fmaf(__shfl(agg1, k, 64), nw1[(D + 16 + k) * 32 + c2], acc);
    const float dn = fmaxf(acc, 0.f);
    float outv = nb2[c2];
    #pragma unroll
    for (int k = 0; k < 32; ++k)
        outv = fmaf(__shfl(dn, k, 32), nw2[k * 32 + c2], outv);
    if (lane < 32) hout[row * 32 + c2] = outv;
}

// ---------------------------------------------------------------------------
// K4a: decoder -> so6[8*512][6]. One wave per (o,n) row.
// ---------------------------------------------------------------------------
__global__ void __launch_bounds__(256) dec_kernel(const float* __restrict__ h2,
                                                  const float* __restrict__ w1,
                                                  const float* __restrict__ b1,
                                                  const float* __restrict__ w2,   // [32][6]
                                                  const float* __restrict__ b2,
                                                  float* __restrict__ so6) {
    int t = threadIdx.x;
    int wave = t >> 6, lane = t & 63;
    int row = blockIdx.x * 4 + wave;   // 0..4095
    int c = lane & 31;
    float hv = h2[row * 32 + c];
    float rh = fmaxf(hv, 0.f);
    float acc = b1[c];
    #pragma unroll
    for (int k = 0; k < 32; ++k)
        acc = fmaf(__shfl(rh, k, 32), w1[k * 32 + c], acc);
    float s = fmaxf(acc, 0.f);
    #pragma unroll
    for (int m = 0; m < 6; ++m) {
        float p = s * w2[c * 6 + m];
        p += __shfl_xor(p, 1); p += __shfl_xor(p, 2); p += __shfl_xor(p, 4);
        p += __shfl_xor(p, 8); p += __shfl_xor(p, 16);
        if (lane == 0) so6[row * 6 + m] = p + b2[m];
    }
}

// ---------------------------------------------------------------------------
// K4b: h_mean + coef MLP + invert_frame + x_out/v_out. One wave per node.
// ---------------------------------------------------------------------------
__global__ void __launch_bounds__(256) final_kernel(const float* __restrict__ h2,
                                                    const float* __restrict__ so6,
                                                    const float* __restrict__ x,
                                                    const float* __restrict__ v,
                                                    const float* __restrict__ ws,
                                                    const float* __restrict__ vw1,
                                                    const float* __restrict__ vb1,
                                                    const float* __restrict__ vw2,
                                                    const float* __restrict__ vb2,
                                                    float* __restrict__ out_hmean,
                                                    float* __restrict__ out_x,
                                                    float* __restrict__ out_v) {
    int t = threadIdx.x;
    int wave = t >> 6, lane = t & 63;
    int n = blockIdx.x * 4 + wave;   // 0..511
    int c = lane & 31;
    float hm = 0.f;
    #pragma unroll
    for (int o = 0; o < 8; ++o) hm += h2[(o * 512 + n) * 32 + c];
    hm *= 0.125f;
    if (lane < 32) out_hmean[n * 32 + c] = hm;
    float rh = fmaxf(hm, 0.f);
    float acc = vb1[c];
    #pragma unroll
    for (int k = 0; k < 32; ++k)
        acc = fmaf(__shfl(rh, k, 32), vw1[k * 32 + c], acc);
    float t1 = fmaxf(acc, 0.f);
    float p = t1 * vw2[c];
    p += __shfl_xor(p, 1); p += __shfl_xor(p, 2); p += __shfl_xor(p, 4);
    p += __shfl_xor(p, 8); p += __shfl_xor(p, 16);
    float coef = p + vb2[0];
    if (lane < 3) {
        int i = lane;
        float dx = 0.f, dv = 0.f;
        #pragma unroll
        for (int o = 0; o < 8; ++o) {
            #pragma unroll
            for (int j = 0; j < 3; ++j) {
                float sgn = ((o >> (2 - j)) & 1) ? -1.f : 1.f;
                float f = sgn * ws[3 + i * 3 + j];
                dx = fmaf(f, so6[(o * 512 + n) * 6 + j], dx);
                dv = fmaf(f, so6[(o * 512 + n) * 6 + 3 + j], dv);
            }
        }
        dx *= 0.125f; dv *= 0.125f;
        float vout = v[n * 3 + i] + dv;
        out_v[n * 3 + i] = vout;
        out_x[n * 3 + i] = x[n * 3 + i] + vout * coef + dx;
    }
}

// ---------------------------------------------------------------------------
extern "C" void kernel_launch(void* const* d_in, const int* in_sizes, int n_in,
                              void* d_out, int out_size, void* d_ws, size_t ws_size,
                              hipStream_t stream) {
    const float* node_feat = (const float*)d_in[0];
    const float* edge      = (const float*)d_in[1];
    const float* x         = (const float*)d_in[2];
    const float* v         = (const float*)d_in[3];
    const float* e0_w1 = (const float*)d_in[4];
    const float* e0_b1 = (const float*)d_in[5];
    const float* e0_w2 = (const float*)d_in[6];
    const float* e0_b2 = (const float*)d_in[7];
    const float* n0_w1 = (const float*)d_in[8];
    const float* n0_b1 = (const float*)d_in[9];
    const float* n0_w2 = (const float*)d_in[10];
    const float* n0_b2 = (const float*)d_in[11];
    const float* e1_w1 = (const float*)d_in[12];
    const float* e1_b1 = (const float*)d_in[13];
    const float* e1_w2 = (const float*)d_in[14];
    const float* e1_b2 = (const float*)d_in[15];
    const float* n1_w1 = (const float*)d_in[16];
    const float* n1_b1 = (const float*)d_in[17];
    const float* n1_w2 = (const float*)d_in[18];
    const float* n1_b2 = (const float*)d_in[19];
    const float* dec_w1 = (const float*)d_in[20];
    const float* dec_b1 = (const float*)d_in[21];
    const float* dec_w2 = (const float*)d_in[22];
    const float* dec_b2 = (const float*)d_in[23];
    const float* vc_w1 = (const float*)d_in[24];
    const float* vc_b1 = (const float*)d_in[25];
    const float* vc_w2 = (const float*)d_in[26];
    const float* vc_b2 = (const float*)d_in[27];

    float* ws  = (float*)d_ws;
    float* out = (float*)d_out;

    float* FR  = ws;                 // 16 floats (center + V)
    float* H0  = ws + 16;            // 8*512*14 = 57344
    float* HA  = H0 + 57344;         // 8*512*32 = 131072
    float* HB  = HA + 131072;        // 131072
    float* PJ  = HB + 131072;        // 131072
    float* PIB = PJ + 131072;        // 131072
    float* SO6 = PIB + 131072;       // 8*512*6 = 24576

    // Output 1: edge_feat passthrough
    hipMemcpyAsync(out + 16384, edge, (size_t)262144 * sizeof(float),
                   hipMemcpyDeviceToDevice, stream);

    frame_kernel<<<1, 256, 0, stream>>>(x, FR);
    h0_kernel<<<16, 256, 0, stream>>>(x, v, node_feat, FR, H0);

    // Layer 0 (D=14)
    pre_kernel<14><<<512, 256, 0, stream>>>(H0, e0_w1, e0_b1, PJ, PIB);
    edge_kernel<14><<<1024, 256, 0, stream>>>(PJ, PIB, edge, H0, e0_w1, e0_w2,
                                              e0_b2, n0_w1, n0_b1, n0_w2, n0_b2, HA);
    // Layer 1 (D=32)
    pre_kernel<32><<<512, 256, 0, stream>>>(HA, e1_w1, e1_b1, PJ, PIB);
    edge_kernel<32><<<1024, 256, 0, stream>>>(PJ, PIB, edge, HA, e1_w1, e1_w2,
                                              e1_b2, n1_w1, n1_b1, n1_w2, n1_b2, HB);
    // Decoder + outputs
    dec_kernel<<<1024, 256, 0, stream>>>(HB, dec_w1, dec_b1, dec_w2, dec_b2, SO6);
    final_kernel<<<128, 256, 0, stream>>>(HB, SO6, x, v, FR, vc_w1, vc_b1, vc_w2,
                                          vc_b2, out, out + 278528, out + 280064);
}